// Round 18
// baseline (295.977 us; speedup 1.0000x reference)
//
#include <hip/hip_runtime.h>
#include <hip/hip_bf16.h>
#include <stdint.h>

// Problem constants
#define MB_  8
#define NQ_  256
#define NKV_ 4096
#define E_   1024
#define H_   16
#define D_   64

typedef __bf16 bf16x8 __attribute__((ext_vector_type(8)));
typedef float  f32x4  __attribute__((ext_vector_type(4)));
typedef unsigned short u16;
typedef unsigned short u16x4 __attribute__((ext_vector_type(4)));
typedef unsigned short u16x8 __attribute__((ext_vector_type(8)));

#define MFMA16(a,b,c) __builtin_amdgcn_mfma_f32_16x16x32_bf16((a),(b),(c),0,0,0)
// Single v_exp_f32 (hardware 2^x). Plain exp2f lowers to accurate OCML
// (~10 insts) and cost ~30us across 268M evals (R15/R16 post-mortem).
#define EXP2(x) __builtin_amdgcn_exp2f(x)

__device__ __forceinline__ u16 f2bf(float f) {
  uint32_t u = __float_as_uint(f);
  u += 0x7fffu + ((u >> 16) & 1u);   // RNE (no NaNs in this workload)
  return (u16)(u >> 16);
}

__device__ __forceinline__ u16x8 pack8(f32x4 a, f32x4 b) {
  u16x8 v;
  v[0] = f2bf(a[0]); v[1] = f2bf(a[1]); v[2] = f2bf(a[2]); v[3] = f2bf(a[3]);
  v[4] = f2bf(b[0]); v[5] = f2bf(b[1]); v[6] = f2bf(b[2]); v[7] = f2bf(b[3]);
  return v;
}

__device__ __forceinline__ void gload_lds16(const void* g, void* l) {
  __builtin_amdgcn_global_load_lds(
      (const __attribute__((address_space(1))) void*)g,
      (__attribute__((address_space(3))) void*)l, 16, 0, 0);
}

// Stage a 128-row x 128-byte bf16 tile (row stride ldbytes) into LDS.
// Swizzle via the GLOBAL source address (rule #21): LDS byte (row,cb) holds
// source (row, cb ^ ((row&7)<<4)).
// NOTE (R5/R9/R10): fusing f32->bf16 conversion into GEMM staging regressed
// every time. NOTE (R15): pipelining attn_stats/pbar at the cost of
// occupancy was ~neutral; keep the simple sync structure.
__device__ __forceinline__ void stage_tile(const char* __restrict__ g, int ldbytes,
                                           char* lds, int t) {
  int srcCB = (((t & 7) ^ ((t >> 3) & 7)) << 4);
  const char* gp = g + (long long)(t >> 3) * ldbytes + srcCB;
  char* lp = lds + ((t >> 6) << 10);
#pragma unroll
  for (int i = 0; i < 4; ++i) {
    gload_lds16(gp + (long long)(32 * i) * ldbytes, lp + i * 4096);
  }
}

__device__ __forceinline__ bf16x8 read_frag(const char* lds, int r, int cb) {
  return *(const bf16x8*)(lds + r * 128 + (cb ^ ((r & 7) << 4)));
}

// ---------------------------------------------------------------------------
// Generic NT GEMM (128x128 tile, BK=64, 256 thr). MODE 0: bf16 C.
// MODE 2: split-K x4 f32 partials (z = ks*8 + m), nontemporal C stores.
// ---------------------------------------------------------------------------
template <int MODE>
__global__ __launch_bounds__(256, 2) void gemm_nt(
    const u16* __restrict__ A, const u16* __restrict__ Bt, void* __restrict__ Cv,
    int lda, int ldb, int ldc, int K,
    long long sA, long long sB, long long sC) {
  __shared__ __align__(16) char smA[16384];
  __shared__ __align__(16) char smB[16384];
  int zz = blockIdx.z;
  int b = (MODE == 2) ? (zz & 7) : zz;
  int ks = (MODE == 2) ? (zz >> 3) : 0;
  long long koff = (long long)ks * 1024;

  unsigned nwg = gridDim.x * gridDim.y;
  unsigned orig = blockIdx.y * gridDim.x + blockIdx.x;
  unsigned cpx = nwg >> 3;
  unsigned swz = (orig & 7) * cpx + (orig >> 3);
  unsigned bx = swz % gridDim.x, by = swz / gridDim.x;

  const char* Ap = (const char*)(A + (long long)b * sA + (long long)by * 128 * lda + koff);
  const char* Bp = (const char*)(Bt + (long long)b * sB + (long long)bx * 128 * ldb + koff);

  int t = threadIdx.x, lane = t & 63;
  int wm = t >> 7, wn = (t >> 6) & 1;
  int rl = lane & 15, kq = lane >> 4;

  f32x4 acc[4][4];
#pragma unroll
  for (int i = 0; i < 4; ++i)
#pragma unroll
    for (int j = 0; j < 4; ++j) acc[i][j] = (f32x4){0.f, 0.f, 0.f, 0.f};

  int ldab = lda * 2, ldbb = ldb * 2;
  for (int k0 = 0; k0 < K; k0 += 64) {
    stage_tile(Ap + k0 * 2, ldab, smA, t);
    stage_tile(Bp + k0 * 2, ldbb, smB, t);
    __syncthreads();
    bf16x8 af[4][2], bf[4][2];
#pragma unroll
    for (int f = 0; f < 4; ++f)
#pragma unroll
      for (int ksl = 0; ksl < 2; ++ksl) {
        af[f][ksl] = read_frag(smA, wm * 64 + f * 16 + rl, ksl * 64 + kq * 16);
        bf[f][ksl] = read_frag(smB, wn * 64 + f * 16 + rl, ksl * 64 + kq * 16);
      }
#pragma unroll
    for (int fm = 0; fm < 4; ++fm)
#pragma unroll
      for (int fn = 0; fn < 4; ++fn) {
        acc[fm][fn] = MFMA16(af[fm][0], bf[fn][0], acc[fm][fn]);
        acc[fm][fn] = MFMA16(af[fm][1], bf[fn][1], acc[fm][fn]);
      }
    __syncthreads();
  }

#pragma unroll
  for (int fm = 0; fm < 4; ++fm)
#pragma unroll
    for (int fn = 0; fn < 4; ++fn)
#pragma unroll
      for (int j = 0; j < 4; ++j) {
        int row = by * 128 + wm * 64 + fm * 16 + kq * 4 + j;
        int col = bx * 128 + wn * 64 + fn * 16 + rl;
        if (MODE == 0) {
          ((u16*)Cv)[(long long)b * sC + (long long)row * ldc + col] = f2bf(acc[fm][fn][j]);
        } else {
          float* dst = (float*)Cv + ((long long)(ks * 8 + b)) * sC +
                       (long long)row * ldc + col;
          __builtin_nontemporal_store(acc[fm][fn][j], dst);
        }
      }
}

// ---------------------------------------------------------------------------
// gemm256 (R8-proven): 256x256 tile, BK=32, 512 threads (8 waves 2Mx4N),
// quad-buffered 128 KB LDS, counted-vmcnt pipeline (T4), raw s_barrier,
// prefetch 2 K-steps ahead, setprio (T5). Used for Kproj (bf16 in).
// ---------------------------------------------------------------------------
__device__ __forceinline__ void stage32(const char* __restrict__ g, int ldbytes,
                                        char* ldsbuf, int t, long long koffB) {
  int w = t >> 6, lane = t & 63;
#pragma unroll
  for (int i = 0; i < 2; ++i) {
    int c = w + i * 8;
    int slot = c * 64 + lane;
    int row = slot >> 2, c16 = slot & 3;
    int srcc = (c16 ^ ((row >> 1) & 3)) << 4;
    gload_lds16(g + (long long)row * ldbytes + koffB + srcc, ldsbuf + c * 1024);
  }
}

__device__ __forceinline__ bf16x8 frag32(const char* ldsbuf, int r, int kq) {
  return *(const bf16x8*)(ldsbuf + r * 64 + ((kq ^ ((r >> 1) & 3)) << 4));
}

__global__ __launch_bounds__(512, 2) void gemm256(
    const u16* __restrict__ A, const u16* __restrict__ Bt, u16* __restrict__ C,
    int lda, int ldb, int ldc, int K) {
  extern __shared__ char lds[];   // 4 bufs x (A 16KB + B 16KB) = 128 KB

  unsigned nwg = gridDim.x * gridDim.y;
  unsigned orig = blockIdx.y * gridDim.x + blockIdx.x;
  unsigned cpx = nwg >> 3;
  unsigned swz = (orig & 7) * cpx + (orig >> 3);
  unsigned bx = swz % gridDim.x, by = swz / gridDim.x;

  const char* Ap = (const char*)(A + (long long)by * 256 * lda);
  const char* Bp = (const char*)(Bt + (long long)bx * 256 * ldb);
  int ldab = lda * 2, ldbb = ldb * 2;

  int t = threadIdx.x, lane = t & 63;
  int wid = t >> 6, wm = wid >> 2, wn = wid & 3;
  int rl = lane & 15, kq = lane >> 4;

  f32x4 acc[8][4];
#pragma unroll
  for (int i = 0; i < 8; ++i)
#pragma unroll
    for (int j = 0; j < 4; ++j) acc[i][j] = (f32x4){0.f, 0.f, 0.f, 0.f};

  stage32(Ap, ldab, lds, t, 0);
  stage32(Bp, ldbb, lds + 16384, t, 0);
  stage32(Ap, ldab, lds + 32768, t, 64);
  stage32(Bp, ldbb, lds + 32768 + 16384, t, 64);
  asm volatile("s_waitcnt vmcnt(4)" ::: "memory");
  asm volatile("s_barrier" ::: "memory");

  int NT = K >> 5;
  for (int ts = 0; ts < NT; ++ts) {
    char* bufA = lds + (ts & 3) * 32768;
    char* bufB = bufA + 16384;
    if (ts + 2 < NT) {
      char* nb = lds + ((ts + 2) & 3) * 32768;
      stage32(Ap, ldab, nb, t, (long long)(ts + 2) << 6);
      stage32(Bp, ldbb, nb + 16384, t, (long long)(ts + 2) << 6);
    }
    bf16x8 af[8], bv[4];
#pragma unroll
    for (int fr = 0; fr < 8; ++fr) af[fr] = frag32(bufA, wm * 128 + fr * 16 + rl, kq);
#pragma unroll
    for (int fc = 0; fc < 4; ++fc) bv[fc] = frag32(bufB, wn * 64 + fc * 16 + rl, kq);
    __builtin_amdgcn_s_setprio(1);
#pragma unroll
    for (int fr = 0; fr < 8; ++fr)
#pragma unroll
      for (int fc = 0; fc < 4; ++fc)
        acc[fr][fc] = MFMA16(af[fr], bv[fc], acc[fr][fc]);
    __builtin_amdgcn_s_setprio(0);
    if (ts + 2 < NT)
      asm volatile("s_waitcnt vmcnt(4)" ::: "memory");
    else
      asm volatile("s_waitcnt vmcnt(0)" ::: "memory");
    asm volatile("s_barrier" ::: "memory");
  }

#pragma unroll
  for (int fr = 0; fr < 8; ++fr)
#pragma unroll
    for (int fc = 0; fc < 4; ++fc)
#pragma unroll
      for (int j = 0; j < 4; ++j) {
        int row = by * 256 + wm * 128 + fr * 16 + kq * 4 + j;
        int col = bx * 256 + wn * 64 + fc * 16 + rl;
        C[(long long)row * ldc + col] = f2bf(acc[fr][fc][j]);
      }
}

// ---------------------------------------------------------------------------
// PV split-K combine: out1 = xq + sum of 4 partials. Fixed order, nt loads.
// ---------------------------------------------------------------------------
__global__ void pv_combine(const float* __restrict__ part, const float* __restrict__ xq,
                           float* __restrict__ out1) {
  int i = blockIdx.x * 256 + threadIdx.x;
  f32x4 s = __builtin_nontemporal_load((const f32x4*)xq + i);
#pragma unroll
  for (int k = 0; k < 4; ++k) {
    f32x4 p = __builtin_nontemporal_load((const f32x4*)(part + (long long)k * 2097152) + i);
    s += p;
  }
  ((f32x4*)out1)[i] = s;
}

// ---------------------------------------------------------------------------
// Pass 1 (R13 structure + hw exp2): row sums of 2^(S'), S' pre-scaled by
// log2(e) (folded into WqT). Simple stage->sync->compute loop; latency hidden
// by 4 blocks/CU occupancy.
// grid = (kt=32, qt=2, z=16: m=z>>1, hhalf=z&1), block = 256 (2x2 waves).
// ---------------------------------------------------------------------------
__global__ __launch_bounds__(256, 4) void attn_stats(
    const u16* __restrict__ qg, const u16* __restrict__ kg,
    float* __restrict__ lstP) {
  __shared__ __align__(16) char smQ[16384];
  __shared__ __align__(16) char smK[16384];
  int kt = blockIdx.x, qt = blockIdx.y;
  int m = blockIdx.z >> 1, hh = blockIdx.z & 1;
  int t = threadIdx.x, lane = t & 63;
  int wm = t >> 7, wn = (t >> 6) & 1;
  int rl = lane & 15, kq = lane >> 4;

  const char* qbase = (const char*)(qg + ((long long)(m * NQ_ + qt * 128)) * 1024);
  const char* kbase = (const char*)(kg + ((long long)(m * NKV_ + kt * 128)) * 1024);

  for (int hi = 0; hi < 8; ++hi) {
    int h = hh * 8 + hi;
    stage_tile(qbase + h * 128, 2048, smQ, t);
    stage_tile(kbase + h * 128, 2048, smK, t);
    __syncthreads();
    bf16x8 kf[4][2], qf[4][2];
#pragma unroll
    for (int f = 0; f < 4; ++f)
#pragma unroll
      for (int ksl = 0; ksl < 2; ++ksl) {
        kf[f][ksl] = read_frag(smK, wm * 64 + f * 16 + rl, ksl * 64 + kq * 16);
        qf[f][ksl] = read_frag(smQ, wn * 64 + f * 16 + rl, ksl * 64 + kq * 16);
      }
    float rs[4] = {0.f, 0.f, 0.f, 0.f};
#pragma unroll
    for (int fm = 0; fm < 4; ++fm)
#pragma unroll
      for (int fn = 0; fn < 4; ++fn) {
        f32x4 sc = (f32x4){0.f, 0.f, 0.f, 0.f};
        sc = MFMA16(kf[fm][0], qf[fn][0], sc);
        sc = MFMA16(kf[fm][1], qf[fn][1], sc);
        rs[fn] += (EXP2(sc[0]) + EXP2(sc[1])) + (EXP2(sc[2]) + EXP2(sc[3]));
      }
#pragma unroll
    for (int fn = 0; fn < 4; ++fn) {
      float v = rs[fn];
      v += __shfl_xor(v, 16);
      v += __shfl_xor(v, 32);
      if (lane < 16) {
        int q = qt * 128 + wn * 64 + fn * 16 + rl;
        lstP[(long long)(kt * 2 + wm) * 32768 + ((m * H_ + h) << 8) + q] = v;
      }
    }
    __syncthreads();
  }
}

// ---------------------------------------------------------------------------
// Merge the 64 (kt x wm) partial sums. Fixed order -> deterministic.
// ---------------------------------------------------------------------------
__global__ void stats_combine(const float* __restrict__ lp, float* __restrict__ lst) {
  int i = blockIdx.x * 256 + threadIdx.x;
  float s = 0.f;
#pragma unroll
  for (int k = 0; k < 64; ++k) s += lp[(long long)k * 32768 + i];
  lst[i] = s;
}

// ---------------------------------------------------------------------------
// Pass 2 (R13 structure + hw exp2): Pbar[m,q,k] = sum_h (hw[h]/l) * 2^(s'_h),
// bf16 out. grid = (kt=32, qt=2, m=8), block = 256.
// ---------------------------------------------------------------------------
__global__ __launch_bounds__(256, 2) void pbar_kernel(
    const u16* __restrict__ qg, const u16* __restrict__ kg,
    const float* __restrict__ lstat,
    const float* __restrict__ rawhw, u16* __restrict__ Pbar) {
  __shared__ __align__(16) char smQ[16384];
  __shared__ __align__(16) char smK[16384];
  __shared__ float scf[2048];
  int kt = blockIdx.x, qt = blockIdx.y, m = blockIdx.z;
  int q0 = qt * 128, k0 = kt * 128;
  int t = threadIdx.x, lane = t & 63;
  int wm = t >> 7, wn = (t >> 6) & 1;
  int rl = lane & 15, kq = lane >> 4;

  float hm = -1e30f;
  for (int i = 0; i < H_; ++i) hm = fmaxf(hm, rawhw[i]);
  float hs = 0.f, hw[H_];
  for (int i = 0; i < H_; ++i) { hw[i] = __expf(rawhw[i] - hm); hs += hw[i]; }
  float hinv = 1.f / hs;
  for (int idx = t; idx < 2048; idx += 256) {
    int h = idx >> 7, r = idx & 127;
    scf[idx] = hw[h] * hinv / lstat[((m * H_ + h) << 8) + q0 + r];
  }

  f32x4 pacc[4][4];
#pragma unroll
  for (int i = 0; i < 4; ++i)
#pragma unroll
    for (int j = 0; j < 4; ++j) pacc[i][j] = (f32x4){0.f, 0.f, 0.f, 0.f};

  const char* qbase = (const char*)(qg + ((long long)(m * NQ_ + q0)) * 1024);
  const char* kbase = (const char*)(kg + ((long long)(m * NKV_ + k0)) * 1024);

  for (int h = 0; h < H_; ++h) {
    stage_tile(qbase + h * 128, 2048, smQ, t);
    stage_tile(kbase + h * 128, 2048, smK, t);
    __syncthreads();  // also orders the scf writes above (first iter)
    bf16x8 af[4][2], bfr[4][2];
#pragma unroll
    for (int f = 0; f < 4; ++f)
#pragma unroll
      for (int ksl = 0; ksl < 2; ++ksl) {
        af[f][ksl] = read_frag(smQ, wm * 64 + f * 16 + rl, ksl * 64 + kq * 16);
        bfr[f][ksl] = read_frag(smK, wn * 64 + f * 16 + rl, ksl * 64 + kq * 16);
      }
#pragma unroll
    for (int fm = 0; fm < 4; ++fm) {
      int rbase = wm * 64 + fm * 16 + kq * 4;
      float cf0 = scf[(h << 7) + rbase + 0];
      float cf1 = scf[(h << 7) + rbase + 1];
      float cf2 = scf[(h << 7) + rbase + 2];
      float cf3 = scf[(h << 7) + rbase + 3];
#pragma unroll
      for (int fn = 0; fn < 4; ++fn) {
        f32x4 sc = (f32x4){0.f, 0.f, 0.f, 0.f};
        sc = MFMA16(af[fm][0], bfr[fn][0], sc);
        sc = MFMA16(af[fm][1], bfr[fn][1], sc);
        pacc[fm][fn][0] += cf0 * EXP2(sc[0]);
        pacc[fm][fn][1] += cf1 * EXP2(sc[1]);
        pacc[fm][fn][2] += cf2 * EXP2(sc[2]);
        pacc[fm][fn][3] += cf3 * EXP2(sc[3]);
      }
    }
    __syncthreads();
  }
#pragma unroll
  for (int fm = 0; fm < 4; ++fm)
#pragma unroll
    for (int fn = 0; fn < 4; ++fn)
#pragma unroll
      for (int j = 0; j < 4; ++j) {
        int row = q0 + wm * 64 + fm * 16 + kq * 4 + j;
        int col = k0 + wn * 64 + fn * 16 + rl;
        Pbar[(((long long)m * NQ_ + row) << 12) + col] = f2bf(pacc[fm][fn][j]);
      }
}

// ---------------------------------------------------------------------------
// prep v4: LDS-FREE register transpose (R17 post-mortem: the LDS round-trip
// + 2.2M bank-conflict cycles + barrier in the transpose blocks were the gap
// to the streaming ceiling). Each thread: 4x4 f32 subtile via 4 coalesced
// float4 nt-loads -> register transpose+convert -> 4x 8B u16x4 stores
// (4 lanes/output row = 32B segments; L2 write-combining merges waves).
// cvt region unchanged (R13-proven). zq blocks also write out0 passthrough.
//   [0, 512):      zq -> zqb (bf16) + out0 (f32), 16 elem/thread
//   [512, 8704):   zkv -> zkvb, 16 elem/thread
//   [8704, 8960):  Wq 64x64 transpose tiles (alpha = 0.125*log2e)
//   [8960, 9216):  Wk tiles
//   [9216, 17408): xkv transpose tiles (nt stores)
// ---------------------------------------------------------------------------
__global__ void prep_kernel(const float* __restrict__ zq, u16* __restrict__ zqb,
                            float* __restrict__ out0,
                            const float* __restrict__ zkv, u16* __restrict__ zkvb,
                            const float* __restrict__ Wq, u16* __restrict__ WqT,
                            const float* __restrict__ Wk, u16* __restrict__ WkT,
                            const float* __restrict__ xkv, u16* __restrict__ xkvT) {
  int bid = blockIdx.x;
  if (bid < 8704) {
    const float* in; u16* out; bool passthru; long long i;
    if (bid < 512) { in = zq; out = zqb; passthru = true; i = (long long)bid * 256 + threadIdx.x; }
    else { in = zkv; out = zkvb; passthru = false; i = (long long)(bid - 512) * 256 + threadIdx.x; }
    const f32x4* p = (const f32x4*)(in + i * 16);
    f32x4 a = __builtin_nontemporal_load(p);
    f32x4 b = __builtin_nontemporal_load(p + 1);
    f32x4 c = __builtin_nontemporal_load(p + 2);
    f32x4 d = __builtin_nontemporal_load(p + 3);
    if (passthru) {
      f32x4* o = (f32x4*)(out0 + i * 16);
      __builtin_nontemporal_store(a, o);
      __builtin_nontemporal_store(b, o + 1);
      __builtin_nontemporal_store(c, o + 2);
      __builtin_nontemporal_store(d, o + 3);
    }
    u16x8* q = (u16x8*)(out + i * 16);
    q[0] = pack8(a, b);
    q[1] = pack8(c, d);
    return;
  }
  const float* in; u16* out; int R, C; float alpha; int r0, c0; bool nts = false;
  if (bid < 8960) {
    int id = bid - 8704;
    in = Wq; out = WqT; R = 1024; C = 1024;
    alpha = 0.125f * 1.44269504088896f;   // SCALE * log2(e): scores become 2^x args
    r0 = (id & 15) * 64; c0 = (id >> 4) * 64;
  } else if (bid < 9216) {
    int id = bid - 8960;
    in = Wk; out = WkT; R = 1024; C = 1024; alpha = 1.0f;
    r0 = (id & 15) * 64; c0 = (id >> 4) * 64;
  } else {
    int id = bid - 9216;
    int bz = id >> 10, rem = id & 1023;
    in = xkv + (long long)bz * NKV_ * E_;
    out = xkvT + (long long)bz * NKV_ * E_;
    R = NKV_; C = E_; alpha = 1.0f;
    r0 = (rem & 63) * 64; c0 = (rem >> 6) * 64;
    nts = true;
  }
  // register 4x4 transpose: thread (t) owns rows r..r+3, cols c..c+3
  int t = threadIdx.x;
  int r = r0 + (t >> 4) * 4;
  int c = c0 + (t & 15) * 4;
  const float* ip = in + (long long)r * C + c;
  f32x4 row0 = __builtin_nontemporal_load((const f32x4*)(ip));
  f32x4 row1 = __builtin_nontemporal_load((const f32x4*)(ip + C));
  f32x4 row2 = __builtin_nontemporal_load((const f32x4*)(ip + 2 * C));
  f32x4 row3 = __builtin_nontemporal_load((const f32x4*)(ip + 3 * C));
#pragma unroll
  for (int j = 0; j < 4; ++j) {
    u16x4 v;
    v[0] = f2bf(alpha * row0[j]);
    v[1] = f2bf(alpha * row1[j]);
    v[2] = f2bf(alpha * row2[j]);
    v[3] = f2bf(alpha * row3[j]);
    u16x4* dst = (u16x4*)(out + (long long)(c + j) * R + r);
    if (nts) __builtin_nontemporal_store(v, dst);
    else *dst = v;
  }
}

// ---------------------------------------------------------------------------
extern "C" void kernel_launch(void* const* d_in, const int* in_sizes, int n_in,
                              void* d_out, int out_size, void* d_ws, size_t ws_size,
                              hipStream_t stream) {
  const float* zq  = (const float*)d_in[0];
  const float* zkv = (const float*)d_in[1];
  const float* xq  = (const float*)d_in[2];
  const float* xkv = (const float*)d_in[3];
  const float* Wq  = (const float*)d_in[4];
  const float* Wk  = (const float*)d_in[5];
  const float* rhw = (const float*)d_in[6];
  float* out = (float*)d_out;

  // Workspace layout (bytes). Total need: ~172 MB.
  char* ws = (char*)d_ws;
  u16* WqT  = (u16*)(ws);                      //  2 MB  (x 0.125*log2e folded)
  u16* WkT  = (u16*)(ws + (2ull << 20));       //  2 MB
  u16* zqb  = (u16*)(ws + (4ull << 20));       //  4 MB  [2048][1024]
  u16* qb   = (u16*)(ws + (8ull << 20));       //  4 MB  [2048][1024] (pre-scaled)
  u16* kb   = (u16*)(ws + (12ull << 20));      // 64 MB  [32768][1024]
  u16* xkvT = (u16*)(ws + (76ull << 20));      // 64 MB  [8][1024][4096]
  char* zr  = ws + (140ull << 20);             // 64 MB region, dual-use:
  u16* zkvb = (u16*)zr;                        //   zkv bf16 (dead after Kproj)
  u16* Pbar = (u16*)zr;                        //   then Pbar [8][256][4096] (16 MB)
  float* lst  = (float*)(zr + (18ull << 20));  //   final sumexp (128 KB)
  float* lstP = (float*)(zr + (20ull << 20));  //   partial sumexp [64][32768] (8 MB)
  float* pvP  = (float*)(zr + (28ull << 20));  //   PV split-K partials (32 MB)

  (void)hipFuncSetAttribute((const void*)gemm256,
                            hipFuncAttributeMaxDynamicSharedMemorySize, 131072);

  // 1. all dtype converts + zq passthrough in one dispatch
  prep_kernel<<<17408, 256, 0, stream>>>(zq, zqb, out, zkv, zkvb,
                                         Wq, WqT, Wk, WkT, xkv, xkvT);

  // 2. projections: Qproj on 128^2; Kproj on the proven bf16 256^2 pipeline
  gemm_nt<0><<<dim3(8, 16, 1), 256, 0, stream>>>(zqb, WqT, qb,
                                                 1024, 1024, 1024, 1024, 0, 0, 0);
  gemm256<<<dim3(4, 128, 1), 512, 131072, stream>>>(zkvb, WkT, kb, 1024, 1024, 1024, 1024);

  // 3. softmax denominators
  attn_stats<<<dim3(32, 2, 16), 256, 0, stream>>>(qb, kb, lstP);
  stats_combine<<<128, 256, 0, stream>>>(lstP, lst);

  // 4. head-collapsed probabilities
  pbar_kernel<<<dim3(32, 2, 8), 256, 0, stream>>>(qb, kb, lst, rhw, Pbar);

  // 5. PV split-K x4 -> f32 partials (nt stores), then combine with residual
  gemm_nt<2><<<dim3(8, 2, 32), 256, 0, stream>>>(Pbar, xkvT, pvP,
                                                 4096, 4096, 1024, 1024,
                                                 256LL * 4096, 1024LL * 4096,
                                                 256LL * 1024);
  pv_combine<<<2048, 256, 0, stream>>>(pvP, xq, out + (long long)MB_ * NQ_ * E_);
}

// Round 19
// 290.525 us; speedup vs baseline: 1.0188x; 1.0188x over previous
//
#include <hip/hip_runtime.h>
#include <hip/hip_bf16.h>
#include <stdint.h>

// Problem constants
#define MB_  8
#define NQ_  256
#define NKV_ 4096
#define E_   1024
#define H_   16
#define D_   64

typedef __bf16 bf16x8 __attribute__((ext_vector_type(8)));
typedef float  f32x4  __attribute__((ext_vector_type(4)));
typedef unsigned short u16;
typedef unsigned short u16x8 __attribute__((ext_vector_type(8)));

#define MFMA16(a,b,c) __builtin_amdgcn_mfma_f32_16x16x32_bf16((a),(b),(c),0,0,0)
// Single v_exp_f32 (hardware 2^x). Plain exp2f lowers to accurate OCML
// (~10 insts) and cost ~30us across 268M evals (R15/R16 post-mortem).
#define EXP2(x) __builtin_amdgcn_exp2f(x)

__device__ __forceinline__ u16 f2bf(float f) {
  uint32_t u = __float_as_uint(f);
  u += 0x7fffu + ((u >> 16) & 1u);   // RNE (no NaNs in this workload)
  return (u16)(u >> 16);
}

__device__ __forceinline__ u16x8 pack8(f32x4 a, f32x4 b) {
  u16x8 v;
  v[0] = f2bf(a[0]); v[1] = f2bf(a[1]); v[2] = f2bf(a[2]); v[3] = f2bf(a[3]);
  v[4] = f2bf(b[0]); v[5] = f2bf(b[1]); v[6] = f2bf(b[2]); v[7] = f2bf(b[3]);
  return v;
}

__device__ __forceinline__ void gload_lds16(const void* g, void* l) {
  __builtin_amdgcn_global_load_lds(
      (const __attribute__((address_space(1))) void*)g,
      (__attribute__((address_space(3))) void*)l, 16, 0, 0);
}

// Stage a 128-row x 128-byte bf16 tile (row stride ldbytes) into LDS.
// Swizzle via the GLOBAL source address (rule #21): LDS byte (row,cb) holds
// source (row, cb ^ ((row&7)<<4)).
// NOTE (R5/R9/R10): fusing f32->bf16 conversion into GEMM staging regressed
// every time. NOTE (R15): pipelining attn_stats/pbar at the cost of
// occupancy was ~neutral. NOTE (R18): LDS-free register transpose in prep
// regressed (+5us: 8B scattered stores beat by LDS-assembled 16B stores).
__device__ __forceinline__ void stage_tile(const char* __restrict__ g, int ldbytes,
                                           char* lds, int t) {
  int srcCB = (((t & 7) ^ ((t >> 3) & 7)) << 4);
  const char* gp = g + (long long)(t >> 3) * ldbytes + srcCB;
  char* lp = lds + ((t >> 6) << 10);
#pragma unroll
  for (int i = 0; i < 4; ++i) {
    gload_lds16(gp + (long long)(32 * i) * ldbytes, lp + i * 4096);
  }
}

__device__ __forceinline__ bf16x8 read_frag(const char* lds, int r, int cb) {
  return *(const bf16x8*)(lds + r * 128 + (cb ^ ((r & 7) << 4)));
}

// ---------------------------------------------------------------------------
// Generic NT GEMM (128x128 tile, BK=64, 256 thr). MODE 0: bf16 C.
// MODE 2: split-K x4 f32 partials (z = ks*8 + m), nontemporal C stores.
// ---------------------------------------------------------------------------
template <int MODE>
__global__ __launch_bounds__(256, 2) void gemm_nt(
    const u16* __restrict__ A, const u16* __restrict__ Bt, void* __restrict__ Cv,
    int lda, int ldb, int ldc, int K,
    long long sA, long long sB, long long sC) {
  __shared__ __align__(16) char smA[16384];
  __shared__ __align__(16) char smB[16384];
  int zz = blockIdx.z;
  int b = (MODE == 2) ? (zz & 7) : zz;
  int ks = (MODE == 2) ? (zz >> 3) : 0;
  long long koff = (long long)ks * 1024;

  unsigned nwg = gridDim.x * gridDim.y;
  unsigned orig = blockIdx.y * gridDim.x + blockIdx.x;
  unsigned cpx = nwg >> 3;
  unsigned swz = (orig & 7) * cpx + (orig >> 3);
  unsigned bx = swz % gridDim.x, by = swz / gridDim.x;

  const char* Ap = (const char*)(A + (long long)b * sA + (long long)by * 128 * lda + koff);
  const char* Bp = (const char*)(Bt + (long long)b * sB + (long long)bx * 128 * ldb + koff);

  int t = threadIdx.x, lane = t & 63;
  int wm = t >> 7, wn = (t >> 6) & 1;
  int rl = lane & 15, kq = lane >> 4;

  f32x4 acc[4][4];
#pragma unroll
  for (int i = 0; i < 4; ++i)
#pragma unroll
    for (int j = 0; j < 4; ++j) acc[i][j] = (f32x4){0.f, 0.f, 0.f, 0.f};

  int ldab = lda * 2, ldbb = ldb * 2;
  for (int k0 = 0; k0 < K; k0 += 64) {
    stage_tile(Ap + k0 * 2, ldab, smA, t);
    stage_tile(Bp + k0 * 2, ldbb, smB, t);
    __syncthreads();
    bf16x8 af[4][2], bf[4][2];
#pragma unroll
    for (int f = 0; f < 4; ++f)
#pragma unroll
      for (int ksl = 0; ksl < 2; ++ksl) {
        af[f][ksl] = read_frag(smA, wm * 64 + f * 16 + rl, ksl * 64 + kq * 16);
        bf[f][ksl] = read_frag(smB, wn * 64 + f * 16 + rl, ksl * 64 + kq * 16);
      }
#pragma unroll
    for (int fm = 0; fm < 4; ++fm)
#pragma unroll
      for (int fn = 0; fn < 4; ++fn) {
        acc[fm][fn] = MFMA16(af[fm][0], bf[fn][0], acc[fm][fn]);
        acc[fm][fn] = MFMA16(af[fm][1], bf[fn][1], acc[fm][fn]);
      }
    __syncthreads();
  }

#pragma unroll
  for (int fm = 0; fm < 4; ++fm)
#pragma unroll
    for (int fn = 0; fn < 4; ++fn)
#pragma unroll
      for (int j = 0; j < 4; ++j) {
        int row = by * 128 + wm * 64 + fm * 16 + kq * 4 + j;
        int col = bx * 128 + wn * 64 + fn * 16 + rl;
        if (MODE == 0) {
          ((u16*)Cv)[(long long)b * sC + (long long)row * ldc + col] = f2bf(acc[fm][fn][j]);
        } else {
          float* dst = (float*)Cv + ((long long)(ks * 8 + b)) * sC +
                       (long long)row * ldc + col;
          __builtin_nontemporal_store(acc[fm][fn][j], dst);
        }
      }
}

// ---------------------------------------------------------------------------
// gemm256 (R8-proven): 256x256 tile, BK=32, 512 threads (8 waves 2Mx4N),
// quad-buffered 128 KB LDS, counted-vmcnt pipeline (T4), raw s_barrier,
// prefetch 2 K-steps ahead, setprio (T5). Used for Kproj (bf16 in).
// ---------------------------------------------------------------------------
__device__ __forceinline__ void stage32(const char* __restrict__ g, int ldbytes,
                                        char* ldsbuf, int t, long long koffB) {
  int w = t >> 6, lane = t & 63;
#pragma unroll
  for (int i = 0; i < 2; ++i) {
    int c = w + i * 8;
    int slot = c * 64 + lane;
    int row = slot >> 2, c16 = slot & 3;
    int srcc = (c16 ^ ((row >> 1) & 3)) << 4;
    gload_lds16(g + (long long)row * ldbytes + koffB + srcc, ldsbuf + c * 1024);
  }
}

__device__ __forceinline__ bf16x8 frag32(const char* ldsbuf, int r, int kq) {
  return *(const bf16x8*)(ldsbuf + r * 64 + ((kq ^ ((r >> 1) & 3)) << 4));
}

__global__ __launch_bounds__(512, 2) void gemm256(
    const u16* __restrict__ A, const u16* __restrict__ Bt, u16* __restrict__ C,
    int lda, int ldb, int ldc, int K) {
  extern __shared__ char lds[];   // 4 bufs x (A 16KB + B 16KB) = 128 KB

  unsigned nwg = gridDim.x * gridDim.y;
  unsigned orig = blockIdx.y * gridDim.x + blockIdx.x;
  unsigned cpx = nwg >> 3;
  unsigned swz = (orig & 7) * cpx + (orig >> 3);
  unsigned bx = swz % gridDim.x, by = swz / gridDim.x;

  const char* Ap = (const char*)(A + (long long)by * 256 * lda);
  const char* Bp = (const char*)(Bt + (long long)bx * 256 * ldb);
  int ldab = lda * 2, ldbb = ldb * 2;

  int t = threadIdx.x, lane = t & 63;
  int wid = t >> 6, wm = wid >> 2, wn = wid & 3;
  int rl = lane & 15, kq = lane >> 4;

  f32x4 acc[8][4];
#pragma unroll
  for (int i = 0; i < 8; ++i)
#pragma unroll
    for (int j = 0; j < 4; ++j) acc[i][j] = (f32x4){0.f, 0.f, 0.f, 0.f};

  stage32(Ap, ldab, lds, t, 0);
  stage32(Bp, ldbb, lds + 16384, t, 0);
  stage32(Ap, ldab, lds + 32768, t, 64);
  stage32(Bp, ldbb, lds + 32768 + 16384, t, 64);
  asm volatile("s_waitcnt vmcnt(4)" ::: "memory");
  asm volatile("s_barrier" ::: "memory");

  int NT = K >> 5;
  for (int ts = 0; ts < NT; ++ts) {
    char* bufA = lds + (ts & 3) * 32768;
    char* bufB = bufA + 16384;
    if (ts + 2 < NT) {
      char* nb = lds + ((ts + 2) & 3) * 32768;
      stage32(Ap, ldab, nb, t, (long long)(ts + 2) << 6);
      stage32(Bp, ldbb, nb + 16384, t, (long long)(ts + 2) << 6);
    }
    bf16x8 af[8], bv[4];
#pragma unroll
    for (int fr = 0; fr < 8; ++fr) af[fr] = frag32(bufA, wm * 128 + fr * 16 + rl, kq);
#pragma unroll
    for (int fc = 0; fc < 4; ++fc) bv[fc] = frag32(bufB, wn * 64 + fc * 16 + rl, kq);
    __builtin_amdgcn_s_setprio(1);
#pragma unroll
    for (int fr = 0; fr < 8; ++fr)
#pragma unroll
      for (int fc = 0; fc < 4; ++fc)
        acc[fr][fc] = MFMA16(af[fr], bv[fc], acc[fr][fc]);
    __builtin_amdgcn_s_setprio(0);
    if (ts + 2 < NT)
      asm volatile("s_waitcnt vmcnt(4)" ::: "memory");
    else
      asm volatile("s_waitcnt vmcnt(0)" ::: "memory");
    asm volatile("s_barrier" ::: "memory");
  }

#pragma unroll
  for (int fr = 0; fr < 8; ++fr)
#pragma unroll
    for (int fc = 0; fc < 4; ++fc)
#pragma unroll
      for (int j = 0; j < 4; ++j) {
        int row = by * 256 + wm * 128 + fr * 16 + kq * 4 + j;
        int col = bx * 256 + wn * 64 + fc * 16 + rl;
        C[(long long)row * ldc + col] = f2bf(acc[fr][fc][j]);
      }
}

// ---------------------------------------------------------------------------
// PV split-K combine: out1 = xq + sum of 4 partials. Fixed order, nt loads.
// ---------------------------------------------------------------------------
__global__ void pv_combine(const float* __restrict__ part, const float* __restrict__ xq,
                           float* __restrict__ out1) {
  int i = blockIdx.x * 256 + threadIdx.x;
  f32x4 s = __builtin_nontemporal_load((const f32x4*)xq + i);
#pragma unroll
  for (int k = 0; k < 4; ++k) {
    f32x4 p = __builtin_nontemporal_load((const f32x4*)(part + (long long)k * 2097152) + i);
    s += p;
  }
  ((f32x4*)out1)[i] = s;
}

// ---------------------------------------------------------------------------
// Pass 1 (R13 structure + hw exp2): row sums of 2^(S'), S' pre-scaled by
// log2(e) (folded into WqT). Simple stage->sync->compute loop; latency hidden
// by 4 blocks/CU occupancy.
// grid = (kt=32, qt=2, z=16: m=z>>1, hhalf=z&1), block = 256 (2x2 waves).
// ---------------------------------------------------------------------------
__global__ __launch_bounds__(256, 4) void attn_stats(
    const u16* __restrict__ qg, const u16* __restrict__ kg,
    float* __restrict__ lstP) {
  __shared__ __align__(16) char smQ[16384];
  __shared__ __align__(16) char smK[16384];
  int kt = blockIdx.x, qt = blockIdx.y;
  int m = blockIdx.z >> 1, hh = blockIdx.z & 1;
  int t = threadIdx.x, lane = t & 63;
  int wm = t >> 7, wn = (t >> 6) & 1;
  int rl = lane & 15, kq = lane >> 4;

  const char* qbase = (const char*)(qg + ((long long)(m * NQ_ + qt * 128)) * 1024);
  const char* kbase = (const char*)(kg + ((long long)(m * NKV_ + kt * 128)) * 1024);

  for (int hi = 0; hi < 8; ++hi) {
    int h = hh * 8 + hi;
    stage_tile(qbase + h * 128, 2048, smQ, t);
    stage_tile(kbase + h * 128, 2048, smK, t);
    __syncthreads();
    bf16x8 kf[4][2], qf[4][2];
#pragma unroll
    for (int f = 0; f < 4; ++f)
#pragma unroll
      for (int ksl = 0; ksl < 2; ++ksl) {
        kf[f][ksl] = read_frag(smK, wm * 64 + f * 16 + rl, ksl * 64 + kq * 16);
        qf[f][ksl] = read_frag(smQ, wn * 64 + f * 16 + rl, ksl * 64 + kq * 16);
      }
    float rs[4] = {0.f, 0.f, 0.f, 0.f};
#pragma unroll
    for (int fm = 0; fm < 4; ++fm)
#pragma unroll
      for (int fn = 0; fn < 4; ++fn) {
        f32x4 sc = (f32x4){0.f, 0.f, 0.f, 0.f};
        sc = MFMA16(kf[fm][0], qf[fn][0], sc);
        sc = MFMA16(kf[fm][1], qf[fn][1], sc);
        rs[fn] += (EXP2(sc[0]) + EXP2(sc[1])) + (EXP2(sc[2]) + EXP2(sc[3]));
      }
#pragma unroll
    for (int fn = 0; fn < 4; ++fn) {
      float v = rs[fn];
      v += __shfl_xor(v, 16);
      v += __shfl_xor(v, 32);
      if (lane < 16) {
        int q = qt * 128 + wn * 64 + fn * 16 + rl;
        lstP[(long long)(kt * 2 + wm) * 32768 + ((m * H_ + h) << 8) + q] = v;
      }
    }
    __syncthreads();
  }
}

// ---------------------------------------------------------------------------
// Merge the 64 (kt x wm) partial sums. Fixed order -> deterministic.
// ---------------------------------------------------------------------------
__global__ void stats_combine(const float* __restrict__ lp, float* __restrict__ lst) {
  int i = blockIdx.x * 256 + threadIdx.x;
  float s = 0.f;
#pragma unroll
  for (int k = 0; k < 64; ++k) s += lp[(long long)k * 32768 + i];
  lst[i] = s;
}

// ---------------------------------------------------------------------------
// Pass 2 (R13 structure + hw exp2): Pbar[m,q,k] = sum_h (hw[h]/l) * 2^(s'_h),
// bf16 out. grid = (kt=32, qt=2, m=8), block = 256.
// ---------------------------------------------------------------------------
__global__ __launch_bounds__(256, 2) void pbar_kernel(
    const u16* __restrict__ qg, const u16* __restrict__ kg,
    const float* __restrict__ lstat,
    const float* __restrict__ rawhw, u16* __restrict__ Pbar) {
  __shared__ __align__(16) char smQ[16384];
  __shared__ __align__(16) char smK[16384];
  __shared__ float scf[2048];
  int kt = blockIdx.x, qt = blockIdx.y, m = blockIdx.z;
  int q0 = qt * 128, k0 = kt * 128;
  int t = threadIdx.x, lane = t & 63;
  int wm = t >> 7, wn = (t >> 6) & 1;
  int rl = lane & 15, kq = lane >> 4;

  float hm = -1e30f;
  for (int i = 0; i < H_; ++i) hm = fmaxf(hm, rawhw[i]);
  float hs = 0.f, hw[H_];
  for (int i = 0; i < H_; ++i) { hw[i] = __expf(rawhw[i] - hm); hs += hw[i]; }
  float hinv = 1.f / hs;
  for (int idx = t; idx < 2048; idx += 256) {
    int h = idx >> 7, r = idx & 127;
    scf[idx] = hw[h] * hinv / lstat[((m * H_ + h) << 8) + q0 + r];
  }

  f32x4 pacc[4][4];
#pragma unroll
  for (int i = 0; i < 4; ++i)
#pragma unroll
    for (int j = 0; j < 4; ++j) pacc[i][j] = (f32x4){0.f, 0.f, 0.f, 0.f};

  const char* qbase = (const char*)(qg + ((long long)(m * NQ_ + q0)) * 1024);
  const char* kbase = (const char*)(kg + ((long long)(m * NKV_ + k0)) * 1024);

  for (int h = 0; h < H_; ++h) {
    stage_tile(qbase + h * 128, 2048, smQ, t);
    stage_tile(kbase + h * 128, 2048, smK, t);
    __syncthreads();  // also orders the scf writes above (first iter)
    bf16x8 af[4][2], bfr[4][2];
#pragma unroll
    for (int f = 0; f < 4; ++f)
#pragma unroll
      for (int ksl = 0; ksl < 2; ++ksl) {
        af[f][ksl] = read_frag(smQ, wm * 64 + f * 16 + rl, ksl * 64 + kq * 16);
        bfr[f][ksl] = read_frag(smK, wn * 64 + f * 16 + rl, ksl * 64 + kq * 16);
      }
#pragma unroll
    for (int fm = 0; fm < 4; ++fm) {
      int rbase = wm * 64 + fm * 16 + kq * 4;
      float cf0 = scf[(h << 7) + rbase + 0];
      float cf1 = scf[(h << 7) + rbase + 1];
      float cf2 = scf[(h << 7) + rbase + 2];
      float cf3 = scf[(h << 7) + rbase + 3];
#pragma unroll
      for (int fn = 0; fn < 4; ++fn) {
        f32x4 sc = (f32x4){0.f, 0.f, 0.f, 0.f};
        sc = MFMA16(af[fm][0], bfr[fn][0], sc);
        sc = MFMA16(af[fm][1], bfr[fn][1], sc);
        pacc[fm][fn][0] += cf0 * EXP2(sc[0]);
        pacc[fm][fn][1] += cf1 * EXP2(sc[1]);
        pacc[fm][fn][2] += cf2 * EXP2(sc[2]);
        pacc[fm][fn][3] += cf3 * EXP2(sc[3]);
      }
    }
    __syncthreads();
  }
#pragma unroll
  for (int fm = 0; fm < 4; ++fm)
#pragma unroll
    for (int fn = 0; fn < 4; ++fn)
#pragma unroll
      for (int j = 0; j < 4; ++j) {
        int row = q0 + wm * 64 + fm * 16 + kq * 4 + j;
        int col = k0 + wn * 64 + fn * 16 + rl;
        Pbar[(((long long)m * NQ_ + row) << 12) + col] = f2bf(pacc[fm][fn][j]);
      }
}

// ---------------------------------------------------------------------------
// prep v3 (R17-proven, best measured): wide-vector converts + nt hygiene;
// LDS 64x65 tile transpose (beats register transpose, R18). zq blocks also
// write the f32 passthrough to out0. WqT alpha folds SCALE * log2(e).
//   [0, 512):      zq -> zqb (bf16) + out0 (f32), 16 elem/thread
//   [512, 8704):   zkv -> zkvb, 16 elem/thread
//   [8704, 8960):  Wq 64x64 transpose tiles (alpha = 0.125*log2e)
//   [8960, 9216):  Wk tiles
//   [9216, 17408): xkv transpose tiles (nt stores)
// ---------------------------------------------------------------------------
__global__ void prep_kernel(const float* __restrict__ zq, u16* __restrict__ zqb,
                            float* __restrict__ out0,
                            const float* __restrict__ zkv, u16* __restrict__ zkvb,
                            const float* __restrict__ Wq, u16* __restrict__ WqT,
                            const float* __restrict__ Wk, u16* __restrict__ WkT,
                            const float* __restrict__ xkv, u16* __restrict__ xkvT) {
  __shared__ float tile[64][65];
  int bid = blockIdx.x;
  if (bid < 8704) {
    const float* in; u16* out; bool passthru; long long i;
    if (bid < 512) { in = zq; out = zqb; passthru = true; i = (long long)bid * 256 + threadIdx.x; }
    else { in = zkv; out = zkvb; passthru = false; i = (long long)(bid - 512) * 256 + threadIdx.x; }
    const f32x4* p = (const f32x4*)(in + i * 16);
    f32x4 a = __builtin_nontemporal_load(p);
    f32x4 b = __builtin_nontemporal_load(p + 1);
    f32x4 c = __builtin_nontemporal_load(p + 2);
    f32x4 d = __builtin_nontemporal_load(p + 3);
    if (passthru) {
      f32x4* o = (f32x4*)(out0 + i * 16);
      __builtin_nontemporal_store(a, o);
      __builtin_nontemporal_store(b, o + 1);
      __builtin_nontemporal_store(c, o + 2);
      __builtin_nontemporal_store(d, o + 3);
    }
    u16x8* q = (u16x8*)(out + i * 16);
    q[0] = pack8(a, b);
    q[1] = pack8(c, d);
    return;
  }
  const float* in; u16* out; int R, C; float alpha; int r0, c0; bool nts = false;
  if (bid < 8960) {
    int id = bid - 8704;
    in = Wq; out = WqT; R = 1024; C = 1024;
    alpha = 0.125f * 1.44269504088896f;   // SCALE * log2(e): scores become 2^x args
    r0 = (id & 15) * 64; c0 = (id >> 4) * 64;
  } else if (bid < 9216) {
    int id = bid - 8960;
    in = Wk; out = WkT; R = 1024; C = 1024; alpha = 1.0f;
    r0 = (id & 15) * 64; c0 = (id >> 4) * 64;
  } else {
    int id = bid - 9216;
    int bz = id >> 10, rem = id & 1023;
    in = xkv + (long long)bz * NKV_ * E_;
    out = xkvT + (long long)bz * NKV_ * E_;
    R = NKV_; C = E_; alpha = 1.0f;
    r0 = (rem & 63) * 64; c0 = (rem >> 6) * 64;
    nts = true;
  }
  int t = threadIdx.x;
  int rr = t >> 4, c4 = t & 15;
#pragma unroll
  for (int i = 0; i < 4; ++i) {
    f32x4 v = __builtin_nontemporal_load(
        (const f32x4*)(in + (long long)(r0 + rr + i * 16) * C + c0 + c4 * 4));
    float* d = &tile[rr + i * 16][c4 * 4];
    d[0] = v[0]; d[1] = v[1]; d[2] = v[2]; d[3] = v[3];
  }
  __syncthreads();
  int cc = t >> 3, r8 = t & 7;
#pragma unroll
  for (int i = 0; i < 2; ++i) {
    int c = cc + i * 32;
    u16x8 v;
#pragma unroll
    for (int j = 0; j < 8; ++j) v[j] = f2bf(alpha * tile[r8 * 8 + j][c]);
    u16x8* dst = (u16x8*)(out + (long long)(c0 + c) * R + r0 + r8 * 8);
    if (nts) __builtin_nontemporal_store(v, dst);
    else *dst = v;
  }
}

// ---------------------------------------------------------------------------
extern "C" void kernel_launch(void* const* d_in, const int* in_sizes, int n_in,
                              void* d_out, int out_size, void* d_ws, size_t ws_size,
                              hipStream_t stream) {
  const float* zq  = (const float*)d_in[0];
  const float* zkv = (const float*)d_in[1];
  const float* xq  = (const float*)d_in[2];
  const float* xkv = (const float*)d_in[3];
  const float* Wq  = (const float*)d_in[4];
  const float* Wk  = (const float*)d_in[5];
  const float* rhw = (const float*)d_in[6];
  float* out = (float*)d_out;

  // Workspace layout (bytes). Total need: ~172 MB.
  char* ws = (char*)d_ws;
  u16* WqT  = (u16*)(ws);                      //  2 MB  (x 0.125*log2e folded)
  u16* WkT  = (u16*)(ws + (2ull << 20));       //  2 MB
  u16* zqb  = (u16*)(ws + (4ull << 20));       //  4 MB  [2048][1024]
  u16* qb   = (u16*)(ws + (8ull << 20));       //  4 MB  [2048][1024] (pre-scaled)
  u16* kb   = (u16*)(ws + (12ull << 20));      // 64 MB  [32768][1024]
  u16* xkvT = (u16*)(ws + (76ull << 20));      // 64 MB  [8][1024][4096]
  char* zr  = ws + (140ull << 20);             // 64 MB region, dual-use:
  u16* zkvb = (u16*)zr;                        //   zkv bf16 (dead after Kproj)
  u16* Pbar = (u16*)zr;                        //   then Pbar [8][256][4096] (16 MB)
  float* lst  = (float*)(zr + (18ull << 20));  //   final sumexp (128 KB)
  float* lstP = (float*)(zr + (20ull << 20));  //   partial sumexp [64][32768] (8 MB)
  float* pvP  = (float*)(zr + (28ull << 20));  //   PV split-K partials (32 MB)

  (void)hipFuncSetAttribute((const void*)gemm256,
                            hipFuncAttributeMaxDynamicSharedMemorySize, 131072);

  // 1. all dtype converts + zq passthrough in one dispatch
  prep_kernel<<<17408, 256, 0, stream>>>(zq, zqb, out, zkv, zkvb,
                                         Wq, WqT, Wk, WkT, xkv, xkvT);

  // 2. projections: Qproj on 128^2; Kproj on the proven bf16 256^2 pipeline
  gemm_nt<0><<<dim3(8, 16, 1), 256, 0, stream>>>(zqb, WqT, qb,
                                                 1024, 1024, 1024, 1024, 0, 0, 0);
  gemm256<<<dim3(4, 128, 1), 512, 131072, stream>>>(zkvb, WkT, kb, 1024, 1024, 1024, 1024);

  // 3. softmax denominators
  attn_stats<<<dim3(32, 2, 16), 256, 0, stream>>>(qb, kb, lstP);
  stats_combine<<<128, 256, 0, stream>>>(lstP, lst);

  // 4. head-collapsed probabilities
  pbar_kernel<<<dim3(32, 2, 8), 256, 0, stream>>>(qb, kb, lst, rhw, Pbar);

  // 5. PV split-K x4 -> f32 partials (nt stores), then combine with residual
  gemm_nt<2><<<dim3(8, 2, 32), 256, 0, stream>>>(Pbar, xkvT, pvP,
                                                 4096, 4096, 1024, 1024,
                                                 256LL * 4096, 1024LL * 4096,
                                                 256LL * 1024);
  pv_combine<<<2048, 256, 0, stream>>>(pvP, xq, out + (long long)MB_ * NQ_ * E_);
}